// Round 1
// baseline (852.360 us; speedup 1.0000x reference)
//
#include <hip/hip_runtime.h>
#include <cmath>

#define NB 8
#define NN 2048
#define FIN 128
#define FOUT 64
#define GAT_ALPHA 0.2f
#define TI 8

// ---------------- Kernel A: Wh = h @ W ; s1 = Wh@a1 ; s2 = Wh@a2 ----------------
__global__ __launch_bounds__(256) void wh_kernel(const float* __restrict__ h,
                                                 const float* __restrict__ W,
                                                 const float* __restrict__ a1,
                                                 const float* __restrict__ a2,
                                                 float* __restrict__ Wh,
                                                 float* __restrict__ s1,
                                                 float* __restrict__ s2) {
    const int wave = threadIdx.x >> 6;
    const int lane = threadIdx.x & 63;
    const int row = blockIdx.x * 4 + wave;      // 0 .. B*N-1
    const float* hrow = h + (size_t)row * FIN;

    float acc = 0.f;
#pragma unroll
    for (int f = 0; f < FIN; ++f) {
        acc = fmaf(hrow[f], W[f * FOUT + lane], acc);  // W read coalesced over lanes
    }
    Wh[(size_t)row * FOUT + lane] = acc;

    float r1 = acc * a1[lane];
    float r2 = acc * a2[lane];
#pragma unroll
    for (int off = 32; off; off >>= 1) {
        r1 += __shfl_xor(r1, off);
        r2 += __shfl_xor(r2, off);
    }
    if (lane == 0) { s1[row] = r1; s2[row] = r2; }
}

// ---------------- Kernel B: fused mask + softmax (no-max trick) + PV + elu ----------------
__global__ __launch_bounds__(256) void attn_kernel(const int* __restrict__ adj,
                                                   const float* __restrict__ Wh,
                                                   const float* __restrict__ s1,
                                                   const float* __restrict__ s2,
                                                   float* __restrict__ out) {
    __shared__ float lds_p[NN * TI];            // [j][r] layout, 64 KB
    __shared__ float lds_part[4 * TI * FOUT];   // 8 KB cross-wave partials
    __shared__ float lds_den[TI];

    const int b  = blockIdx.x >> 8;             // 256 blocks per batch (2048/TI)
    const int i0 = (blockIdx.x & 255) * TI;
    const int t  = threadIdx.x;
    const int wave = t >> 6, lane = t & 63;

    if (t < TI) lds_den[t] = 0.f;
    __syncthreads();

    float s1v[TI];
#pragma unroll
    for (int r = 0; r < TI; ++r) s1v[r] = s1[b * NN + i0 + r];

    const int* adjBase = adj + ((size_t)b * NN + i0) * NN;
    float dsum[TI];
#pragma unroll
    for (int r = 0; r < TI; ++r) dsum[r] = 0.f;

    // ---- Phase 1: single pass over adj rows; p into LDS; denominators ----
    for (int k = 0; k < NN / 256; ++k) {
        const int j = t + k * 256;
        const float s2v = s2[b * NN + j];
#pragma unroll
        for (int r = 0; r < TI; ++r) {
            const int a = adjBase[(size_t)r * NN + j];   // coalesced over threads
            const float x = s1v[r] + s2v;
            const float e = x > 0.f ? x : GAT_ALPHA * x;
            const float p = (a > 0) ? __expf(e) : 0.f;   // no-max softmax: scores bounded
            lds_p[j * TI + r] = p;
            dsum[r] += p;
        }
    }
#pragma unroll
    for (int r = 0; r < TI; ++r) {
        float v = dsum[r];
#pragma unroll
        for (int off = 32; off; off >>= 1) v += __shfl_xor(v, off);
        if (lane == 0) atomicAdd(&lds_den[r], v);
    }
    __syncthreads();

    // ---- Phase 2: PV. Wave w owns j in [w*512, w*512+512), all 8 rows ----
    float acc[TI];
#pragma unroll
    for (int r = 0; r < TI; ++r) acc[r] = 0.f;
    const float* WhB = Wh + (size_t)b * NN * FOUT;
    const int j0 = wave * (NN / 4);
    for (int j = j0; j < j0 + NN / 4; ++j) {
        const float wh = WhB[(size_t)j * FOUT + lane];   // coalesced, L2-resident
        const float4* p4 = (const float4*)&lds_p[j * TI];
        const float4 pa = p4[0], pb = p4[1];             // broadcast reads
        acc[0] = fmaf(pa.x, wh, acc[0]);
        acc[1] = fmaf(pa.y, wh, acc[1]);
        acc[2] = fmaf(pa.z, wh, acc[2]);
        acc[3] = fmaf(pa.w, wh, acc[3]);
        acc[4] = fmaf(pb.x, wh, acc[4]);
        acc[5] = fmaf(pb.y, wh, acc[5]);
        acc[6] = fmaf(pb.z, wh, acc[6]);
        acc[7] = fmaf(pb.w, wh, acc[7]);
    }
#pragma unroll
    for (int r = 0; r < TI; ++r) lds_part[(wave * TI + r) * FOUT + lane] = acc[r];
    __syncthreads();

    // ---- Phase 3: cross-wave reduce, normalize, ELU, store ----
    for (int idx = t; idx < TI * FOUT; idx += 256) {
        const int r = idx >> 6, o = idx & 63;
        const float num = lds_part[(0 * TI + r) * FOUT + o]
                        + lds_part[(1 * TI + r) * FOUT + o]
                        + lds_part[(2 * TI + r) * FOUT + o]
                        + lds_part[(3 * TI + r) * FOUT + o];
        const float v = num / lds_den[r];
        out[((size_t)(b * NN + i0 + r)) * FOUT + o] = v > 0.f ? v : expm1f(v);
    }
}

extern "C" void kernel_launch(void* const* d_in, const int* in_sizes, int n_in,
                              void* d_out, int out_size, void* d_ws, size_t ws_size,
                              hipStream_t stream) {
    const float* h   = (const float*)d_in[0];
    const int*   adj = (const int*)d_in[1];
    const float* W   = (const float*)d_in[2];
    const float* a1  = (const float*)d_in[3];
    const float* a2  = (const float*)d_in[4];
    float* out = (float*)d_out;

    float* Wh = (float*)d_ws;                       // B*N*FOUT = 4 MB
    float* s1 = Wh + (size_t)NB * NN * FOUT;        // 64 KB
    float* s2 = s1 + (size_t)NB * NN;               // 64 KB

    wh_kernel<<<(NB * NN) / 4, 256, 0, stream>>>(h, W, a1, a2, Wh, s1, s2);
    attn_kernel<<<(NB * NN) / TI, 256, 0, stream>>>(adj, Wh, s1, s2, out);
}

// Round 2
// 275.519 us; speedup vs baseline: 3.0936x; 3.0936x over previous
//
#include <hip/hip_runtime.h>
#include <hip/hip_bf16.h>
#include <cmath>

#define NB 8
#define NN 2048
#define FIN 128
#define FOUT 64
#define GAT_ALPHA 0.2f

typedef __attribute__((ext_vector_type(8))) short short8;
typedef __attribute__((ext_vector_type(4))) float f32x4;

static __device__ __forceinline__ ushort f2bf(float x) {
    __hip_bfloat16 hb = __float2bfloat16(x);
    return __builtin_bit_cast(ushort, hb);
}

// ---------------- Kernel A: Wh = h@W (fp32); store bf16 TRANSPOSED WhT[b][o][j];
// ---------------- s1 = Wh@a1, s2 = Wh@a2
__global__ __launch_bounds__(256) void wh_kernel(const float* __restrict__ h,
                                                 const float* __restrict__ W,
                                                 const float* __restrict__ a1,
                                                 const float* __restrict__ a2,
                                                 ushort* __restrict__ whT,
                                                 float* __restrict__ s1,
                                                 float* __restrict__ s2) {
    __shared__ float tile[64][65];   // +1 pad: conflict-free column reads
    const int t = threadIdx.x;
    const int wave = t >> 6, lane = t & 63;
    const int b = blockIdx.x >> 5;           // 32 blocks per batch
    const int j0 = (blockIdx.x & 31) << 6;   // 64-row j-tile
    const float a1v = a1[lane], a2v = a2[lane];

    for (int it = 0; it < 16; ++it) {
        const int jl = wave * 16 + it;
        const int row = b * NN + j0 + jl;
        const float4* h4 = (const float4*)(h + (size_t)row * FIN);
        float acc0 = 0.f, acc1 = 0.f, acc2 = 0.f, acc3 = 0.f;  // 4 chains: break dep latency
#pragma unroll
        for (int f4 = 0; f4 < FIN / 4; ++f4) {
            const float4 hv = h4[f4];
            acc0 = fmaf(hv.x, W[(f4 * 4 + 0) * FOUT + lane], acc0);
            acc1 = fmaf(hv.y, W[(f4 * 4 + 1) * FOUT + lane], acc1);
            acc2 = fmaf(hv.z, W[(f4 * 4 + 2) * FOUT + lane], acc2);
            acc3 = fmaf(hv.w, W[(f4 * 4 + 3) * FOUT + lane], acc3);
        }
        const float acc = (acc0 + acc1) + (acc2 + acc3);
        tile[jl][lane] = acc;
        float r1 = acc * a1v, r2 = acc * a2v;
#pragma unroll
        for (int off = 32; off; off >>= 1) { r1 += __shfl_xor(r1, off); r2 += __shfl_xor(r2, off); }
        if (lane == 0) { s1[row] = r1; s2[row] = r2; }
    }
    __syncthreads();
    // transposed bf16 write: lanes sweep j (coalesced 128B stores)
#pragma unroll
    for (int rep = 0; rep < 16; ++rep) {
        const int o = rep * 4 + wave;
        whT[((size_t)(b * FOUT + o)) * NN + j0 + lane] = f2bf(tile[lane][o]);
    }
}

// ---------------- Kernel B: fused mask + no-max softmax + MFMA PV + elu ----------------
__global__ __launch_bounds__(256) void attn_kernel(const int* __restrict__ adj,
                                                   const ushort* __restrict__ whT,
                                                   const float* __restrict__ s1,
                                                   const float* __restrict__ s2,
                                                   float* __restrict__ out) {
    __shared__ float s2l[NN];              // 8 KB
    __shared__ float red[4][16][FOUT];     // 16 KB cross-wave partials
    __shared__ float den[4][16];

    const int t = threadIdx.x, w = t >> 6, lane = t & 63;
    const int b = blockIdx.x >> 7;
    const int i0 = (blockIdx.x & 127) << 4;     // 16 i-rows per block

    for (int idx = t; idx < NN; idx += 256) s2l[idx] = s2[b * NN + idx];

    const int rrow = lane & 15;     // A-fragment row  = local i-row
    const int kg   = lane >> 4;     // k-group (8 j's each)
    const float s1v = s1[b * NN + i0 + rrow];
    const int* adjRow = adj + ((size_t)(b * NN + i0 + rrow)) * NN;
    const ushort* whB = whT + (size_t)b * FOUT * NN;
    __syncthreads();

    f32x4 acc[4] = {{0.f,0.f,0.f,0.f},{0.f,0.f,0.f,0.f},{0.f,0.f,0.f,0.f},{0.f,0.f,0.f,0.f}};
    float dsum = 0.f;
    const int jbase = w * (NN / 4) + kg * 8;    // this wave's j-chunk, this lane's k-group

    for (int step = 0; step < 16; ++step) {
        const int jb = jbase + step * 32;
        const int4 av0 = *(const int4*)(adjRow + jb);
        const int4 av1 = *(const int4*)(adjRow + jb + 4);
        const float4 sv0 = *(const float4*)(s2l + jb);      // LDS broadcast, conflict-free
        const float4 sv1 = *(const float4*)(s2l + jb + 4);

        float p[8];
        {
            const int   a[8] = {av0.x, av0.y, av0.z, av0.w, av1.x, av1.y, av1.z, av1.w};
            const float s[8] = {sv0.x, sv0.y, sv0.z, sv0.w, sv1.x, sv1.y, sv1.z, sv1.w};
#pragma unroll
            for (int r = 0; r < 8; ++r) {
                const float x = s1v + s[r];
                const float e = x > 0.f ? x : GAT_ALPHA * x;
                p[r] = (a[r] > 0) ? __expf(e) : 0.f;   // no-max softmax: |score| <= ~6
            }
        }
        dsum += ((p[0] + p[1]) + (p[2] + p[3])) + ((p[4] + p[5]) + (p[6] + p[7]));

        short8 af;
#pragma unroll
        for (int r = 0; r < 8; ++r) af[r] = (short)f2bf(p[r]);

#pragma unroll
        for (int nt = 0; nt < 4; ++nt) {
            const short8 bf = *(const short8*)(whB + ((size_t)(nt * 16 + rrow)) * NN + jb);
            acc[nt] = __builtin_amdgcn_mfma_f32_16x16x32_bf16(af, bf, acc[nt], 0, 0, 0);
        }
    }

    // denominator: reduce over the 4 k-groups holding the same i-row
    dsum += __shfl_xor(dsum, 16);
    dsum += __shfl_xor(dsum, 32);
    if (lane < 16) den[w][lane] = dsum;

    // C/D layout: lane holds D[row=(lane>>4)*4+q][col=lane&15] per n-tile
#pragma unroll
    for (int nt = 0; nt < 4; ++nt)
#pragma unroll
        for (int q = 0; q < 4; ++q)
            red[w][kg * 4 + q][nt * 16 + rrow] = acc[nt][q];
    __syncthreads();

    // cross-wave reduce, normalize, ELU, coalesced store
#pragma unroll
    for (int rep = 0; rep < 4; ++rep) {
        const int idx = rep * 256 + t;
        const int r = idx >> 6, o = idx & 63;
        const float num = red[0][r][o] + red[1][r][o] + red[2][r][o] + red[3][r][o];
        const float d = den[0][r] + den[1][r] + den[2][r] + den[3][r];
        const float v = num / d;
        out[((size_t)(b * NN + i0 + r)) * FOUT + o] = v > 0.f ? v : expm1f(v);
    }
}

extern "C" void kernel_launch(void* const* d_in, const int* in_sizes, int n_in,
                              void* d_out, int out_size, void* d_ws, size_t ws_size,
                              hipStream_t stream) {
    const float* h   = (const float*)d_in[0];
    const int*   adj = (const int*)d_in[1];
    const float* W   = (const float*)d_in[2];
    const float* a1  = (const float*)d_in[3];
    const float* a2  = (const float*)d_in[4];
    float* out = (float*)d_out;

    ushort* whT = (ushort*)d_ws;                                  // 2 MB
    float*  s1  = (float*)((char*)d_ws + (size_t)NB * FOUT * NN * sizeof(ushort));
    float*  s2  = s1 + (size_t)NB * NN;

    wh_kernel<<<NB * 32, 256, 0, stream>>>(h, W, a1, a2, whT, s1, s2);
    attn_kernel<<<NB * 128, 256, 0, stream>>>(adj, whT, s1, s2, out);
}

// Round 3
// 237.145 us; speedup vs baseline: 3.5943x; 1.1618x over previous
//
#include <hip/hip_runtime.h>
#include <hip/hip_bf16.h>
#include <cmath>

#define NB 8
#define NN 2048
#define FIN 128
#define FOUT 64
#define GAT_ALPHA 0.2f

typedef __attribute__((ext_vector_type(8))) short short8;
typedef __attribute__((ext_vector_type(4))) float f32x4;

static __device__ __forceinline__ ushort f2bf(float x) {
    __hip_bfloat16 hb = __float2bfloat16(x);
    return __builtin_bit_cast(ushort, hb);
}
static __device__ __forceinline__ short8 pack8(const float4 a, const float4 b) {
    short8 r;
    r[0] = (short)f2bf(a.x); r[1] = (short)f2bf(a.y); r[2] = (short)f2bf(a.z); r[3] = (short)f2bf(a.w);
    r[4] = (short)f2bf(b.x); r[5] = (short)f2bf(b.y); r[6] = (short)f2bf(b.z); r[7] = (short)f2bf(b.w);
    return r;
}

// ---- Kernel 0: WT[o][k] = bf16(W[k][o]);  wa1 = W@a1, wa2 = W@a2 (fp32) ----
__global__ void wt_kernel(const float* __restrict__ W, const float* __restrict__ a1,
                          const float* __restrict__ a2, ushort* __restrict__ WT,
                          float* __restrict__ wa) {
    const int t = threadIdx.x;
    const int o = t & 63, kg = t >> 6;
#pragma unroll
    for (int kk = 0; kk < 32; ++kk) {
        const int k = kg * 32 + kk;
        WT[o * FIN + k] = f2bf(W[k * FOUT + o]);
    }
    if (t < FIN) {
        float x1 = 0.f, x2 = 0.f;
        for (int o2 = 0; o2 < FOUT; ++o2) {
            const float w = W[t * FOUT + o2];
            x1 = fmaf(w, a1[o2], x1);
            x2 = fmaf(w, a2[o2], x2);
        }
        wa[t] = x1; wa[FIN + t] = x2;
    }
}

// ---- Kernel A: Wh via MFMA -> whT[b][o][j] bf16;  s1 = h@wa1, s2 = h@wa2 (exact fp32) ----
__global__ __launch_bounds__(256) void wh_kernel(const float* __restrict__ h,
                                                 const ushort* __restrict__ WT,
                                                 const float* __restrict__ wa,
                                                 ushort* __restrict__ whT,
                                                 float* __restrict__ s1,
                                                 float* __restrict__ s2) {
    const int t = threadIdx.x, w = t >> 6, lane = t & 63;
    const int rrow = lane & 15, kg = lane >> 4;
    const int j0 = blockIdx.x * 16;              // global row base (never crosses batch)
    const int b = j0 >> 11, jloc = j0 & (NN - 1);
    const float* hrow = h + (size_t)(j0 + rrow) * FIN + kg * 8;

    float4 hv[8];
    short8 af[4];
#pragma unroll
    for (int ks = 0; ks < 4; ++ks) {
        hv[2 * ks]     = *(const float4*)(hrow + ks * 32);
        hv[2 * ks + 1] = *(const float4*)(hrow + ks * 32 + 4);
        af[ks] = pack8(hv[2 * ks], hv[2 * ks + 1]);
    }
    f32x4 acc = {0.f, 0.f, 0.f, 0.f};
#pragma unroll
    for (int ks = 0; ks < 4; ++ks) {
        const short8 bf = *(const short8*)(WT + (size_t)(w * 16 + rrow) * FIN + ks * 32 + kg * 8);
        acc = __builtin_amdgcn_mfma_f32_16x16x32_bf16(af[ks], bf, acc, 0, 0, 0);
    }
    // D: lane holds Wh[j0 + kg*4+q][o = w*16 + rrow]
#pragma unroll
    for (int q = 0; q < 4; ++q)
        whT[(((size_t)b * FOUT + w * 16 + rrow) << 11) + jloc + kg * 4 + q] = f2bf(acc[q]);

    if (w == 0) {   // s1/s2: exact fp32, one wave per block
        float p1 = 0.f, p2 = 0.f;
#pragma unroll
        for (int ks = 0; ks < 4; ++ks) {
#pragma unroll
            for (int e = 0; e < 8; ++e) {
                const float4 hq = hv[2 * ks + (e >> 2)];
                const float x = (e & 3) == 0 ? hq.x : (e & 3) == 1 ? hq.y : (e & 3) == 2 ? hq.z : hq.w;
                const int k = ks * 32 + kg * 8 + e;
                p1 = fmaf(x, wa[k], p1);
                p2 = fmaf(x, wa[FIN + k], p2);
            }
        }
        p1 += __shfl_xor(p1, 16); p1 += __shfl_xor(p1, 32);
        p2 += __shfl_xor(p2, 16); p2 += __shfl_xor(p2, 32);
        if (lane < 16) { s1[j0 + lane] = p1; s2[j0 + lane] = p2; }
    }
}

// ---- Kernel B: fused mask + no-max softmax + MFMA PV over a j-half; partial num/den ----
__global__ __launch_bounds__(256) void attn_kernel(const int* __restrict__ adj,
                                                   const ushort* __restrict__ whT,
                                                   const float* __restrict__ s1,
                                                   const float* __restrict__ s2,
                                                   float* __restrict__ pnum,
                                                   float* __restrict__ pden) {
    __shared__ float smem[4 * 16 * FOUT];   // 16 KB; first 4 KB doubles as s2 stage
    __shared__ float den[4][16];
    const int t = threadIdx.x, w = t >> 6, lane = t & 63;
    const int rrow = lane & 15, kg = lane >> 4;
    const int b = blockIdx.x >> 8, blk = blockIdx.x & 255;
    const int i0 = (blk >> 1) << 4, half = blk & 1;
    const int jh = half * (NN / 2);

    for (int idx = t; idx < NN / 2; idx += 256) smem[idx] = s2[b * NN + jh + idx];
    const float s1v = s1[b * NN + i0 + rrow];
    const int* adjRow = adj + ((size_t)(b * NN + i0 + rrow)) * NN + jh;
    const ushort* whB = whT + (size_t)b * FOUT * NN + jh;
    __syncthreads();

    f32x4 acc[4] = {{0,0,0,0},{0,0,0,0},{0,0,0,0},{0,0,0,0}};
    float dsum = 0.f;
    const int jb0 = w * 256 + kg * 8;

    int4 buf[2][2];                          // distance-2 prefetch; loop fully unrolled
    buf[0][0] = *(const int4*)(adjRow + jb0);
    buf[0][1] = *(const int4*)(adjRow + jb0 + 4);
    buf[1][0] = *(const int4*)(adjRow + jb0 + 32);
    buf[1][1] = *(const int4*)(adjRow + jb0 + 36);

#pragma unroll
    for (int step = 0; step < 8; ++step) {
        const int jb = jb0 + step * 32;
        const int4 c0 = buf[step & 1][0];
        const int4 c1 = buf[step & 1][1];
        if (step + 2 < 8) {
            buf[step & 1][0] = *(const int4*)(adjRow + jb + 64);
            buf[step & 1][1] = *(const int4*)(adjRow + jb + 68);
        }
        const float4 sv0 = *(const float4*)(smem + jb);
        const float4 sv1 = *(const float4*)(smem + jb + 4);
        const int   a[8] = {c0.x, c0.y, c0.z, c0.w, c1.x, c1.y, c1.z, c1.w};
        const float s[8] = {sv0.x, sv0.y, sv0.z, sv0.w, sv1.x, sv1.y, sv1.z, sv1.w};
        short8 af;
        float ds = 0.f;
#pragma unroll
        for (int r = 0; r < 8; ++r) {
            const float x = s1v + s[r];
            const float e = __expf(fmaxf(x, GAT_ALPHA * x));  // no-max softmax: |score| <= ~6
            const float p = (a[r] > 0) ? e : 0.f;
            ds += p;
            af[r] = (short)f2bf(p);
        }
        dsum += ds;
#pragma unroll
        for (int nt = 0; nt < 4; ++nt) {
            const short8 bf = *(const short8*)(whB + ((size_t)(nt * 16 + rrow) << 11) + jb);
            acc[nt] = __builtin_amdgcn_mfma_f32_16x16x32_bf16(af, bf, acc[nt], 0, 0, 0);
        }
    }
    dsum += __shfl_xor(dsum, 16);
    dsum += __shfl_xor(dsum, 32);
    if (lane < 16) den[w][lane] = dsum;
    __syncthreads();                 // s2 stage reads done; reuse smem as reduction buffer

#pragma unroll
    for (int nt = 0; nt < 4; ++nt)
#pragma unroll
        for (int q = 0; q < 4; ++q)
            smem[(w * 16 + kg * 4 + q) * FOUT + nt * 16 + rrow] = acc[nt][q];
    __syncthreads();

    const size_t obase = (((size_t)half * NB + b) * NN + i0) * FOUT;
#pragma unroll
    for (int rep = 0; rep < 4; ++rep) {
        const int idx = rep * 256 + t;
        const int r = idx >> 6, o = idx & 63;
        pnum[obase + (size_t)r * FOUT + o] = smem[r * FOUT + o] + smem[(16 + r) * FOUT + o]
                                          + smem[(32 + r) * FOUT + o] + smem[(48 + r) * FOUT + o];
    }
    if (t < 16) pden[((size_t)half * NB + b) * NN + i0 + t] =
        den[0][t] + den[1][t] + den[2][t] + den[3][t];
}

// ---- Kernel C: combine halves, normalize, ELU ----
__global__ __launch_bounds__(256) void reduce_kernel(const float* __restrict__ pnum,
                                                     const float* __restrict__ pden,
                                                     float* __restrict__ out) {
    const int idx = blockIdx.x * 256 + threadIdx.x;
    const int bi = idx >> 6;
    const float num = pnum[idx] + pnum[idx + (size_t)NB * NN * FOUT];
    const float d = pden[bi] + pden[bi + NB * NN];
    const float v = num / d;
    out[idx] = v > 0.f ? v : expm1f(v);
}

extern "C" void kernel_launch(void* const* d_in, const int* in_sizes, int n_in,
                              void* d_out, int out_size, void* d_ws, size_t ws_size,
                              hipStream_t stream) {
    const float* h   = (const float*)d_in[0];
    const int*   adj = (const int*)d_in[1];
    const float* W   = (const float*)d_in[2];
    const float* a1  = (const float*)d_in[3];
    const float* a2  = (const float*)d_in[4];
    float* out = (float*)d_out;

    char* ws = (char*)d_ws;
    ushort* whT = (ushort*)ws;  ws += (size_t)NB * FOUT * NN * sizeof(ushort);   // 2 MB
    ushort* WT  = (ushort*)ws;  ws += (size_t)FOUT * FIN * sizeof(ushort);       // 16 KB
    float*  wa  = (float*)ws;   ws += (size_t)2 * FIN * sizeof(float);           // 1 KB
    float*  s1  = (float*)ws;   ws += (size_t)NB * NN * sizeof(float);
    float*  s2  = (float*)ws;   ws += (size_t)NB * NN * sizeof(float);
    float*  pnum = (float*)ws;  ws += (size_t)2 * NB * NN * FOUT * sizeof(float); // 8 MB
    float*  pden = (float*)ws;  ws += (size_t)2 * NB * NN * sizeof(float);

    wt_kernel<<<1, 256, 0, stream>>>(W, a1, a2, WT, wa);
    wh_kernel<<<NB * NN / 16, 256, 0, stream>>>(h, WT, wa, whT, s1, s2);
    attn_kernel<<<NB * 256, 256, 0, stream>>>(adj, whT, s1, s2, pnum, pden);
    reduce_kernel<<<NB * NN * FOUT / 256, 256, 0, stream>>>(pnum, pden, out);
}